// Round 1
// baseline (18545.119 us; speedup 1.0000x reference)
//
#include <hip/hip_runtime.h>
#include <hip/hip_bf16.h>
#include <hip/hip_cooperative_groups.h>

namespace cg = cooperative_groups;

// Problem constants
#define BSN   2500   // nodes
#define TT    400    // time steps
#define DIN   16     // input dim
#define HS    32     // hidden dim
#define G4    128    // 4*HS
#define NBLK  157    // blocks (16 rows each)
#define ROWS  16     // nodes per block (MFMA M-tile)
#define MPAD  (NBLK * ROWS)   // 2512 padded rows
#define KPAD  2528            // 79*32, K padded for 16x16x32 MFMA
#define NCHUNK 79
#define HPAD  36              // LDS row pad: 36 floats = 144B = 9*16B (float4-aligned, conflict-safe)

typedef __attribute__((ext_vector_type(8))) __bf16 bf16x8;
typedef __attribute__((ext_vector_type(4))) float floatx4;

__device__ __forceinline__ float sigmoid_fast(float v) {
    return 1.0f / (1.0f + __expf(-v));   // v->-inf: exp->inf -> 0 ; v->+inf: -> 1. No NaN.
}
__device__ __forceinline__ float tanh_fast(float v) {
    float e = __expf(2.0f * v);          // e->0 -> -1 ; e->inf -> 1. No NaN.
    return 1.0f - 2.0f / (e + 1.0f);
}
__device__ __forceinline__ unsigned short f2bf(float f) {
    union { float f; unsigned u; } x; x.f = f;
    unsigned r = x.u + 0x7fffu + ((x.u >> 16) & 1u);  // round-to-nearest-even
    return (unsigned short)(r >> 16);
}

// One-time per launch: adj fp32 [2500][2500] -> bf16 zero-padded [2512][2528].
// Padded COLUMNS must be zero (they multiply garbage q entries); padded rows are don't-care.
__global__ void prep_adj(const float* __restrict__ adj, unsigned short* __restrict__ adj_bf) {
    size_t idx = (size_t)blockIdx.x * blockDim.x + threadIdx.x;
    const size_t total = (size_t)MPAD * KPAD;
    const size_t stride = (size_t)gridDim.x * blockDim.x;
    for (; idx < total; idx += stride) {
        int r = (int)(idx / KPAD);
        int k = (int)(idx - (size_t)r * KPAD);
        float v = (r < BSN && k < BSN) ? adj[(size_t)r * BSN + k] : 0.0f;
        adj_bf[idx] = f2bf(v);
    }
}

// Persistent cooperative kernel: the whole T=400 recurrence in one launch.
// Block b owns nodes [16b, 16b+16); h,c live in LDS the whole time.
// One grid.sync per step; qT double-buffered so writes of step t+1 never race reads of step t.
__global__ void __launch_bounds__(256, 1) rgcn_main(
    const float* __restrict__ x,      // [BSN][TT][DIN]
    const float* __restrict__ W_ih,   // [DIN][G4]
    const float* __restrict__ W_hh,   // [HS][G4]
    const float* __restrict__ bias,   // [G4]
    const float* __restrict__ W_q,    // [HS][HS]
    const float* __restrict__ b_q,    // [HS]
    const float* __restrict__ W_d,    // [HS]
    const float* __restrict__ b_d,    // [1]
    const unsigned short* __restrict__ adj_bf, // [MPAD][KPAD] bf16
    unsigned short* __restrict__ qT,  // [2][HS][KPAD] bf16 (q transposed: row=hidden, col=node)
    float* __restrict__ out)          // [BSN][TT]
{
    const int tid  = threadIdx.x;
    const int blk  = blockIdx.x;
    const int base = blk * ROWS;
    const int wv   = tid >> 6;        // wave 0..3
    const int lane = tid & 63;

    __shared__ __align__(16) float x_lds[ROWS][DIN];
    __shared__ __align__(16) float h_lds[ROWS][HPAD];
    __shared__ __align__(16) float c_lds[ROWS][HPAD];
    __shared__ __align__(16) float q_lds[ROWS][HPAD];
    __shared__ float gates_lds[ROWS][G4];       // activated i,f,g,o
    __shared__ float part[4][2][16][16];        // per-wave MFMA partials [wave][ntile][row][col]

    // ---- persistent per-thread weights (registers, loaded once) ----
    // Gate mapping: wave wv computes nodes 4wv..4wv+3; thread covers gate cols u2 and u2+64.
    const int u2 = tid & 63;
    float wih0[DIN], wih1[DIN], whh0[HS], whh1[HS];
#pragma unroll
    for (int k = 0; k < DIN; k++) { wih0[k] = W_ih[k*G4 + u2]; wih1[k] = W_ih[k*G4 + u2 + 64]; }
#pragma unroll
    for (int k = 0; k < HS; k++)  { whh0[k] = W_hh[k*G4 + u2]; whh1[k] = W_hh[k*G4 + u2 + 64]; }
    const float bu0 = bias[u2], bu1 = bias[u2 + 64];

    // q / update mapping: thread = (node nq & nq+8, hidden hq)
    const int hq = tid & 31;
    const int nq = tid >> 5;   // 0..7
    float wq[HS];
#pragma unroll
    for (int k = 0; k < HS; k++) wq[k] = W_q[k*HS + hq];
    const float bqv = b_q[hq];
    const float wdv = W_d[hq];
    const float bdv = b_d[0];

    // init state h=c=0
    for (int i = tid; i < ROWS * HPAD; i += 256) {
        (&h_lds[0][0])[i] = 0.0f;
        (&c_lds[0][0])[i] = 0.0f;
    }

    cg::grid_group grid = cg::this_grid();
    __syncthreads();

    for (int t = 0; t < TT; t++) {
        // ---- stage x_t for owned nodes ----
        {
            int node = tid >> 4, k = tid & 15;
            int gn = base + node;
            x_lds[node][k] = (gn < BSN) ? x[(size_t)gn * (TT*DIN) + (size_t)t*DIN + k] : 0.0f;
        }
        __syncthreads();

        // ---- P1a: gates (fp32, weights in regs, h/x broadcast from LDS) ----
#pragma unroll
        for (int j = 0; j < 4; j++) {
            const int nn = wv*4 + j;
            float a0 = bu0, a1 = bu1;
#pragma unroll
            for (int k4 = 0; k4 < DIN/4; k4++) {
                float4 xv = *(const float4*)&x_lds[nn][k4*4];
                a0 = fmaf(xv.x, wih0[k4*4+0], a0); a1 = fmaf(xv.x, wih1[k4*4+0], a1);
                a0 = fmaf(xv.y, wih0[k4*4+1], a0); a1 = fmaf(xv.y, wih1[k4*4+1], a1);
                a0 = fmaf(xv.z, wih0[k4*4+2], a0); a1 = fmaf(xv.z, wih1[k4*4+2], a1);
                a0 = fmaf(xv.w, wih0[k4*4+3], a0); a1 = fmaf(xv.w, wih1[k4*4+3], a1);
            }
#pragma unroll
            for (int k4 = 0; k4 < HS/4; k4++) {
                float4 hv = *(const float4*)&h_lds[nn][k4*4];
                a0 = fmaf(hv.x, whh0[k4*4+0], a0); a1 = fmaf(hv.x, whh1[k4*4+0], a1);
                a0 = fmaf(hv.y, whh0[k4*4+1], a0); a1 = fmaf(hv.y, whh1[k4*4+1], a1);
                a0 = fmaf(hv.z, whh0[k4*4+2], a0); a1 = fmaf(hv.z, whh1[k4*4+2], a1);
                a0 = fmaf(hv.w, whh0[k4*4+3], a0); a1 = fmaf(hv.w, whh1[k4*4+3], a1);
            }
            // cols u2 in [0,64): i|f -> sigmoid. col u2+64: g (tanh) if u2<32 else o (sigmoid).
            gates_lds[nn][u2]      = sigmoid_fast(a0);
            gates_lds[nn][u2 + 64] = (u2 < HS) ? tanh_fast(a1) : sigmoid_fast(a1);
        }

        // ---- P1b: q = tanh(h @ W_q + b_q) ----
#pragma unroll
        for (int j = 0; j < 2; j++) {
            const int nn = nq + j*8;
            float a = bqv;
#pragma unroll
            for (int k4 = 0; k4 < HS/4; k4++) {
                float4 hv = *(const float4*)&h_lds[nn][k4*4];
                a = fmaf(hv.x, wq[k4*4+0], a);
                a = fmaf(hv.y, wq[k4*4+1], a);
                a = fmaf(hv.z, wq[k4*4+2], a);
                a = fmaf(hv.w, wq[k4*4+3], a);
            }
            q_lds[nn][hq] = tanh_fast(a);
        }
        __syncthreads();

        // ---- publish q (bf16, transposed) to the step-parity buffer ----
        {
            unsigned short* qbuf = qT + (size_t)(t & 1) * (HS * KPAD);
            const int node = tid & 15;
            const int h0 = tid >> 4;  // 0..15
            qbuf[(size_t)h0        * KPAD + base + node] = f2bf(q_lds[node][h0]);
            qbuf[(size_t)(h0 + 16) * KPAD + base + node] = f2bf(q_lds[node][h0 + 16]);
        }
        __threadfence();
        grid.sync();

        // ---- P2: agg = adj_rows @ q via mfma_f32_16x16x32_bf16, K split over 4 waves ----
        {
            const unsigned short* qbuf = qT + (size_t)(t & 1) * (HS * KPAD);
            floatx4 acc0 = {0.f,0.f,0.f,0.f}, acc1 = {0.f,0.f,0.f,0.f};
            const int mcol = lane & 15;     // A row-in-tile / B col-in-tile / D col
            const int kb   = lane >> 4;     // k-group
            const unsigned short* arow = adj_bf + (size_t)(base + mcol) * KPAD + kb*8;
            const unsigned short* q0   = qbuf + (size_t)mcol        * KPAD + kb*8;
            const unsigned short* q1   = qbuf + (size_t)(mcol + 16) * KPAD + kb*8;
            for (int c = wv; c < NCHUNK; c += 4) {
                const int ko = c * 32;
                bf16x8 av = *(const bf16x8*)(arow + ko);
                bf16x8 b0 = *(const bf16x8*)(q0 + ko);
                bf16x8 b1 = *(const bf16x8*)(q1 + ko);
                acc0 = __builtin_amdgcn_mfma_f32_16x16x32_bf16(av, b0, acc0, 0, 0, 0);
                acc1 = __builtin_amdgcn_mfma_f32_16x16x32_bf16(av, b1, acc1, 0, 0, 0);
            }
            // D layout: col=lane&15, row=(lane>>4)*4+reg  [measured m89/m91]
#pragma unroll
            for (int r = 0; r < 4; r++) {
                part[wv][0][kb*4 + r][mcol] = acc0[r];
                part[wv][1][kb*4 + r][mcol] = acc1[r];
            }
        }
        __syncthreads();

        // ---- P3: cell/hidden update + fused output head ----
        {
            const int ntile = hq >> 4, col = hq & 15;
#pragma unroll
            for (int j = 0; j < 2; j++) {
                const int nn = nq + j*8;
                float agg = part[0][ntile][nn][col] + part[1][ntile][nn][col]
                          + part[2][ntile][nn][col] + part[3][ntile][nn][col];
                float iv = gates_lds[nn][hq];
                float fv = gates_lds[nn][HS + hq];
                float gv = gates_lds[nn][2*HS + hq];
                float ov = gates_lds[nn][3*HS + hq];
                float cv = fv * (c_lds[nn][hq] + agg) + iv * gv;
                float hv = ov * tanh_fast(cv);
                c_lds[nn][hq] = cv;
                h_lds[nn][hq] = hv;
                // out[n][t] = h . W_d + b_d ; reduce over the 32 hq lanes of this half-wave
                float p = hv * wdv;
                p += __shfl_xor(p, 16);
                p += __shfl_xor(p, 8);
                p += __shfl_xor(p, 4);
                p += __shfl_xor(p, 2);
                p += __shfl_xor(p, 1);
                if (hq == 0) {
                    int gn = base + nn;
                    if (gn < BSN) out[(size_t)gn * TT + t] = p + bdv;
                }
            }
        }
        __syncthreads();
    }
}

extern "C" void kernel_launch(void* const* d_in, const int* in_sizes, int n_in,
                              void* d_out, int out_size, void* d_ws, size_t ws_size,
                              hipStream_t stream) {
    const float* x    = (const float*)d_in[0];
    const float* adj  = (const float*)d_in[1];
    const float* W_ih = (const float*)d_in[2];
    const float* W_hh = (const float*)d_in[3];
    const float* bias = (const float*)d_in[4];
    const float* W_q  = (const float*)d_in[5];
    const float* b_q  = (const float*)d_in[6];
    const float* W_d  = (const float*)d_in[7];
    const float* b_d  = (const float*)d_in[8];
    float* out = (float*)d_out;

    // workspace: adj_bf16 [2512][2528] (12.7 MB) then qT [2][32][2528] (316 KB)
    unsigned short* adj_bf = (unsigned short*)d_ws;
    unsigned short* qT = adj_bf + (size_t)MPAD * KPAD;

    hipLaunchKernelGGL(prep_adj, dim3(2048), dim3(256), 0, stream, adj, adj_bf);

    const unsigned short* adj_bf_c = adj_bf;
    void* args[] = {
        (void*)&x, (void*)&W_ih, (void*)&W_hh, (void*)&bias, (void*)&W_q,
        (void*)&b_q, (void*)&W_d, (void*)&b_d, (void*)&adj_bf_c, (void*)&qT, (void*)&out
    };
    hipLaunchCooperativeKernel((void*)rgcn_main, dim3(NBLK), dim3(256), args, 0, stream);
}

// Round 2
// 13721.198 us; speedup vs baseline: 1.3516x; 1.3516x over previous
//
#include <hip/hip_runtime.h>
#include <hip/hip_bf16.h>
#include <hip/hip_cooperative_groups.h>

// Problem constants
#define BSN   2500   // nodes
#define TT    400    // time steps
#define DIN   16     // input dim
#define HS    32     // hidden dim
#define G4    128    // 4*HS
#define NBLK  157    // blocks (16 rows each)
#define ROWS  16     // nodes per block (MFMA M-tile)
#define MPAD  (NBLK * ROWS)   // 2512 padded rows
#define KPAD  2528            // 79*32, K padded for 16x16x32 MFMA
#define NCHUNK 79
#define HPAD  36              // LDS row pad: float4-aligned, conflict-safe

typedef __attribute__((ext_vector_type(8))) __bf16 bf16x8;
typedef __attribute__((ext_vector_type(4))) float floatx4;
typedef unsigned short ushort_t;

__device__ __forceinline__ float sigmoid_fast(float v) {
    return 1.0f / (1.0f + __expf(-v));
}
__device__ __forceinline__ float tanh_fast(float v) {
    float e = __expf(2.0f * v);
    return 1.0f - 2.0f / (e + 1.0f);
}
__device__ __forceinline__ ushort_t f2bf(float f) {
    union { float f; unsigned u; } x; x.f = f;
    unsigned r = x.u + 0x7fffu + ((x.u >> 16) & 1u);  // RNE
    return (ushort_t)(r >> 16);
}

// Per-launch prep: adj fp32 -> bf16 zero-padded [MPAD][KPAD]; zero qT; reset barrier.
// (d_ws is re-poisoned 0xAA before every launch, so ALL of this must re-run each launch.)
__global__ void prep(const float* __restrict__ adj, ushort_t* __restrict__ adj_bf,
                     ushort_t* __restrict__ qT, unsigned* __restrict__ bar) {
    const size_t idx0 = (size_t)blockIdx.x * blockDim.x + threadIdx.x;
    const size_t stride = (size_t)gridDim.x * blockDim.x;
    const size_t total = (size_t)MPAD * KPAD;
    for (size_t idx = idx0; idx < total; idx += stride) {
        int r = (int)(idx / KPAD);
        int k = (int)(idx - (size_t)r * KPAD);
        float v = (r < BSN && k < BSN) ? adj[(size_t)r * BSN + k] : 0.0f;
        adj_bf[idx] = f2bf(v);
    }
    for (size_t idx = idx0; idx < (size_t)2 * HS * KPAD; idx += stride) qT[idx] = 0;
    if (idx0 < 64) bar[idx0] = 0;
}

// Persistent cooperative kernel. Block b owns nodes [16b,16b+16).
// adj tile lives in LDS (immune to the per-step L2 invalidation the cross-XCD
// q exchange requires). Custom split barrier: arrive after publishing q, then
// do all block-local work (x stage + gates), then wait.
__global__ void __launch_bounds__(256, 1) rgcn_main(
    const float* __restrict__ x,      // [BSN][TT][DIN]
    const float* __restrict__ W_ih,   // [DIN][G4]
    const float* __restrict__ W_hh,   // [HS][G4]
    const float* __restrict__ bias,   // [G4]
    const float* __restrict__ W_q,    // [HS][HS]
    const float* __restrict__ b_q,    // [HS]
    const float* __restrict__ W_d,    // [HS]
    const float* __restrict__ b_d,    // [1]
    const ushort_t* __restrict__ adj_bf, // [MPAD][KPAD] bf16
    ushort_t* __restrict__ qT,        // [2][HS][KPAD] bf16 (row=hidden, col=node)
    unsigned* __restrict__ bar,       // [0]=count, [32]=generation (separate lines)
    float* __restrict__ out)          // [BSN][TT]
{
    const int tid  = threadIdx.x;
    const int blk  = blockIdx.x;
    const int base = blk * ROWS;
    const int wv   = tid >> 6;
    const int lane = tid & 63;

    __shared__ __align__(16) ushort_t adj_lds[ROWS * KPAD];   // 79 KB, staged once
    __shared__ __align__(16) float x_lds[ROWS][DIN];
    __shared__ __align__(16) float h_lds[ROWS][HPAD];
    __shared__ __align__(16) float c_lds[ROWS][HPAD];
    __shared__ __align__(16) float q_lds[ROWS][HPAD];
    __shared__ float gates_lds[ROWS][G4];
    __shared__ float part[4][2][16][16];

    // ---- persistent per-thread weights ----
    const int u2 = tid & 63;
    float wih0[DIN], wih1[DIN], whh0[HS], whh1[HS];
#pragma unroll
    for (int k = 0; k < DIN; k++) { wih0[k] = W_ih[k*G4 + u2]; wih1[k] = W_ih[k*G4 + u2 + 64]; }
#pragma unroll
    for (int k = 0; k < HS; k++)  { whh0[k] = W_hh[k*G4 + u2]; whh1[k] = W_hh[k*G4 + u2 + 64]; }
    const float bu0 = bias[u2], bu1 = bias[u2 + 64];

    const int hq = tid & 31;
    const int nq = tid >> 5;   // 0..7
    float wq[HS];
#pragma unroll
    for (int k = 0; k < HS; k++) wq[k] = W_q[k*HS + hq];
    const float bqv = b_q[hq];
    const float wdv = W_d[hq];
    const float bdv = b_d[0];

    // ---- stage adj rows to LDS (once) ----
    {
        const uint4* src = (const uint4*)(adj_bf + (size_t)base * KPAD);
        uint4* dst = (uint4*)adj_lds;
        const int n16 = ROWS * KPAD / 8;   // uint4 count = 5056
        for (int i = tid; i < n16; i += 256) dst[i] = src[i];
    }
    // init state
    for (int i = tid; i < ROWS * HPAD; i += 256) {
        (&h_lds[0][0])[i] = 0.0f;
        (&c_lds[0][0])[i] = 0.0f;
    }
    __syncthreads();

    unsigned* cnt = bar;
    unsigned* gen = bar + 32;

    for (int t = 0; t < TT; t++) {
        const unsigned phase = (unsigned)(t + 1);

        // ---- P1b: q = tanh(h @ W_q + b_q) (reads h from prev step; synced) ----
#pragma unroll
        for (int j = 0; j < 2; j++) {
            const int nn = nq + j*8;
            float a = bqv;
#pragma unroll
            for (int k4 = 0; k4 < HS/4; k4++) {
                float4 hv = *(const float4*)&h_lds[nn][k4*4];
                a = fmaf(hv.x, wq[k4*4+0], a);
                a = fmaf(hv.y, wq[k4*4+1], a);
                a = fmaf(hv.z, wq[k4*4+2], a);
                a = fmaf(hv.w, wq[k4*4+3], a);
            }
            q_lds[nn][hq] = tanh_fast(a);
        }
        __syncthreads();

        // ---- publish q (bf16, transposed) to parity buffer ----
        {
            ushort_t* qbuf = qT + (size_t)(t & 1) * (HS * KPAD);
            const int node = tid & 15;
            const int h0 = tid >> 4;  // 0..15
            qbuf[(size_t)h0        * KPAD + base + node] = f2bf(q_lds[node][h0]);
            qbuf[(size_t)(h0 + 16) * KPAD + base + node] = f2bf(q_lds[node][h0 + 16]);
        }
        __threadfence();        // release: drain + write back our q stores
        __syncthreads();        // all waves fenced before the block arrives

        // ---- barrier ARRIVE (tid 0 only) ----
        if (tid == 0) {
            unsigned prev = atomicAdd(cnt, 1u);
            if (prev == NBLK - 1) {
                __hip_atomic_store(cnt, 0u, __ATOMIC_RELAXED, __HIP_MEMORY_SCOPE_AGENT);
                __hip_atomic_store(gen, phase, __ATOMIC_RELEASE, __HIP_MEMORY_SCOPE_AGENT);
            }
        }

        // ==== overlap window: block-local work while other blocks arrive ====
        // stage x_t (wave-local mapping: wave wv loads exactly nodes 4wv..4wv+3)
        {
            const int node = tid >> 4, k = tid & 15;
            const int gn = base + node;
            x_lds[node][k] = (gn < BSN) ? x[(size_t)gn * (TT*DIN) + (size_t)t*DIN + k] : 0.0f;
        }
        // gates (reads h_lds [synced], x_lds [same-wave ordered])
#pragma unroll
        for (int j = 0; j < 4; j++) {
            const int nn = wv*4 + j;
            float a0 = bu0, a1 = bu1;
#pragma unroll
            for (int k4 = 0; k4 < DIN/4; k4++) {
                float4 xv = *(const float4*)&x_lds[nn][k4*4];
                a0 = fmaf(xv.x, wih0[k4*4+0], a0); a1 = fmaf(xv.x, wih1[k4*4+0], a1);
                a0 = fmaf(xv.y, wih0[k4*4+1], a0); a1 = fmaf(xv.y, wih1[k4*4+1], a1);
                a0 = fmaf(xv.z, wih0[k4*4+2], a0); a1 = fmaf(xv.z, wih1[k4*4+2], a1);
                a0 = fmaf(xv.w, wih0[k4*4+3], a0); a1 = fmaf(xv.w, wih1[k4*4+3], a1);
            }
#pragma unroll
            for (int k4 = 0; k4 < HS/4; k4++) {
                float4 hv = *(const float4*)&h_lds[nn][k4*4];
                a0 = fmaf(hv.x, whh0[k4*4+0], a0); a1 = fmaf(hv.x, whh1[k4*4+0], a1);
                a0 = fmaf(hv.y, whh0[k4*4+1], a0); a1 = fmaf(hv.y, whh1[k4*4+1], a1);
                a0 = fmaf(hv.z, whh0[k4*4+2], a0); a1 = fmaf(hv.z, whh1[k4*4+2], a1);
                a0 = fmaf(hv.w, whh0[k4*4+3], a0); a1 = fmaf(hv.w, whh1[k4*4+3], a1);
            }
            gates_lds[nn][u2]      = sigmoid_fast(a0);
            gates_lds[nn][u2 + 64] = (u2 < HS) ? tanh_fast(a1) : sigmoid_fast(a1);
        }

        // ---- barrier WAIT ----
        if (tid == 0) {
            while (__hip_atomic_load(gen, __ATOMIC_ACQUIRE, __HIP_MEMORY_SCOPE_AGENT) < phase)
                __builtin_amdgcn_s_sleep(1);
        }
        __syncthreads();
        __threadfence();        // acquire: invalidate L1/L2 so qT reads are fresh

        // ---- P2: agg = adj(LDS) @ q(global) via mfma_f32_16x16x32_bf16 ----
        {
            const ushort_t* qbuf = qT + (size_t)(t & 1) * (HS * KPAD);
            floatx4 acc0 = {0.f,0.f,0.f,0.f}, acc1 = {0.f,0.f,0.f,0.f};
            const int mcol = lane & 15;
            const int kb   = lane >> 4;
            const ushort_t* arow = adj_lds + mcol * KPAD + kb*8;     // LDS
            const ushort_t* q0   = qbuf + (size_t)mcol        * KPAD + kb*8;
            const ushort_t* q1   = qbuf + (size_t)(mcol + 16) * KPAD + kb*8;
            for (int c = wv; c < NCHUNK; c += 4) {
                const int ko = c * 32;
                bf16x8 av = *(const bf16x8*)(arow + ko);
                bf16x8 b0 = *(const bf16x8*)(q0 + ko);
                bf16x8 b1 = *(const bf16x8*)(q1 + ko);
                acc0 = __builtin_amdgcn_mfma_f32_16x16x32_bf16(av, b0, acc0, 0, 0, 0);
                acc1 = __builtin_amdgcn_mfma_f32_16x16x32_bf16(av, b1, acc1, 0, 0, 0);
            }
            // D layout: col=lane&15, row=(lane>>4)*4+reg
#pragma unroll
            for (int r = 0; r < 4; r++) {
                part[wv][0][kb*4 + r][mcol] = acc0[r];
                part[wv][1][kb*4 + r][mcol] = acc1[r];
            }
        }
        __syncthreads();

        // ---- P3: cell/hidden update + fused output head ----
        {
            const int ntile = hq >> 4, col = hq & 15;
#pragma unroll
            for (int j = 0; j < 2; j++) {
                const int nn = nq + j*8;
                float agg = part[0][ntile][nn][col] + part[1][ntile][nn][col]
                          + part[2][ntile][nn][col] + part[3][ntile][nn][col];
                float iv = gates_lds[nn][hq];
                float fv = gates_lds[nn][HS + hq];
                float gv = gates_lds[nn][2*HS + hq];
                float ov = gates_lds[nn][3*HS + hq];
                float cv = fv * (c_lds[nn][hq] + agg) + iv * gv;
                float hv = ov * tanh_fast(cv);
                c_lds[nn][hq] = cv;
                h_lds[nn][hq] = hv;
                float p = hv * wdv;
                p += __shfl_xor(p, 16);
                p += __shfl_xor(p, 8);
                p += __shfl_xor(p, 4);
                p += __shfl_xor(p, 2);
                p += __shfl_xor(p, 1);
                if (hq == 0) {
                    int gn = base + nn;
                    if (gn < BSN) out[(size_t)gn * TT + t] = p + bdv;
                }
            }
        }
        __syncthreads();
    }
}

extern "C" void kernel_launch(void* const* d_in, const int* in_sizes, int n_in,
                              void* d_out, int out_size, void* d_ws, size_t ws_size,
                              hipStream_t stream) {
    const float* x    = (const float*)d_in[0];
    const float* adj  = (const float*)d_in[1];
    const float* W_ih = (const float*)d_in[2];
    const float* W_hh = (const float*)d_in[3];
    const float* bias = (const float*)d_in[4];
    const float* W_q  = (const float*)d_in[5];
    const float* b_q  = (const float*)d_in[6];
    const float* W_d  = (const float*)d_in[7];
    const float* b_d  = (const float*)d_in[8];
    float* out = (float*)d_out;

    // ws: adj_bf16 [2512][2528] (12.7 MB) | qT [2][32][2528] (316 KB) | barrier (256 B)
    ushort_t* adj_bf = (ushort_t*)d_ws;
    ushort_t* qT = adj_bf + (size_t)MPAD * KPAD;
    unsigned* bar = (unsigned*)(qT + (size_t)2 * HS * KPAD);

    hipLaunchKernelGGL(prep, dim3(2048), dim3(256), 0, stream, adj, adj_bf, qT, bar);

    const ushort_t* adj_bf_c = adj_bf;
    void* args[] = {
        (void*)&x, (void*)&W_ih, (void*)&W_hh, (void*)&bias, (void*)&W_q,
        (void*)&b_q, (void*)&W_d, (void*)&b_d, (void*)&adj_bf_c, (void*)&qT,
        (void*)&bar, (void*)&out
    };
    hipLaunchCooperativeKernel((void*)rgcn_main, dim3(NBLK), dim3(256), args, 0, stream);
}

// Round 3
// 4681.316 us; speedup vs baseline: 3.9615x; 2.9311x over previous
//
#include <hip/hip_runtime.h>
#include <hip/hip_bf16.h>

// Problem constants
#define BSN   2500   // nodes
#define TT    400    // time steps
#define DIN   16     // input dim
#define HS    32     // hidden dim
#define G4    128    // 4*HS
#define NBLK  157    // blocks (16 rows each)
#define ROWS  16     // nodes per block (MFMA M-tile)
#define MPAD  (NBLK * ROWS)   // 2512 padded rows
#define KPAD  2528            // 79*32, K padded for 16x16x32 MFMA
#define NCHUNK 79
#define ADJW  2536            // adj LDS row stride (ushorts): 5072 B == 20 banks -> 2-way only
#define HPAD  36              // fp32 LDS row pad
#define FLAGSTRIDE 16         // uints between flags (64 B)

typedef __attribute__((ext_vector_type(8))) __bf16 bf16x8;
typedef __attribute__((ext_vector_type(4))) float floatx4;
typedef unsigned short ushort_t;
typedef unsigned long long u64_t;

__device__ __forceinline__ float sigmoid_fast(float v) {
    return 1.0f / (1.0f + __expf(-v));
}
__device__ __forceinline__ float tanh_fast(float v) {
    float e = __expf(2.0f * v);
    return 1.0f - 2.0f / (e + 1.0f);
}
__device__ __forceinline__ ushort_t f2bf(float f) {
    union { float f; unsigned u; } x; x.f = f;
    unsigned r = x.u + 0x7fffu + ((x.u >> 16) & 1u);  // RNE
    return (ushort_t)(r >> 16);
}

// Per-launch prep: adj fp32 -> bf16 zero-padded [MPAD][KPAD]; zero qT; zero flags.
// d_ws is re-poisoned 0xAA before every timed launch, so all of this re-runs each launch.
__global__ void prep(const float* __restrict__ adj, ushort_t* __restrict__ adj_bf,
                     ushort_t* __restrict__ qT, unsigned* __restrict__ flags) {
    const size_t idx0 = (size_t)blockIdx.x * blockDim.x + threadIdx.x;
    const size_t stride = (size_t)gridDim.x * blockDim.x;
    const size_t total = (size_t)MPAD * KPAD;
    for (size_t idx = idx0; idx < total; idx += stride) {
        int r = (int)(idx / KPAD);
        int k = (int)(idx - (size_t)r * KPAD);
        float v = (r < BSN && k < BSN) ? adj[(size_t)r * BSN + k] : 0.0f;
        adj_bf[idx] = f2bf(v);
    }
    for (size_t idx = idx0; idx < (size_t)2 * HS * KPAD; idx += stride) qT[idx] = 0;
    if (idx0 < NBLK * FLAGSTRIDE) flags[idx0] = 0;
}

// Persistent cooperative kernel. Block b owns nodes [16b,16b+16).
// Cross-XCD q exchange goes through the LLC explicitly (agent-scope relaxed
// atomics: write-through stores, L2-bypassing loads). NO cache-wide
// writeback/invalidate anywhere -> L2 keeps x/weights hot across steps.
// Barrier: per-block generation flags; split arrive/wait with gate compute in
// the overlap window.
__global__ void __launch_bounds__(256, 1) rgcn_main(
    const float* __restrict__ x,      // [BSN][TT][DIN]
    const float* __restrict__ W_ih,   // [DIN][G4]
    const float* __restrict__ W_hh,   // [HS][G4]
    const float* __restrict__ bias,   // [G4]
    const float* __restrict__ W_q,    // [HS][HS]
    const float* __restrict__ b_q,    // [HS]
    const float* __restrict__ W_d,    // [HS]
    const float* __restrict__ b_d,    // [1]
    const ushort_t* __restrict__ adj_bf, // [MPAD][KPAD] bf16
    ushort_t* __restrict__ qT,        // [2][HS][KPAD] bf16 (row=hidden, col=node)
    unsigned* __restrict__ flags,     // [NBLK] generation flags, FLAGSTRIDE apart
    float* __restrict__ out)          // [BSN][TT]
{
    const int tid  = threadIdx.x;
    const int blk  = blockIdx.x;
    const int base = blk * ROWS;
    const int wv   = tid >> 6;
    const int lane = tid & 63;

    __shared__ __align__(16) ushort_t adj_lds[ROWS * ADJW];   // ~81 KB, staged once
    __shared__ __align__(16) float x_lds[ROWS][DIN];
    __shared__ __align__(16) float h_lds[ROWS][HPAD];
    __shared__ __align__(16) float c_lds[ROWS][HPAD];
    __shared__ __align__(16) float q_lds[ROWS][HPAD];
    __shared__ float gates_lds[ROWS][G4];
    __shared__ float part[4][2][16][16];

    // ---- persistent per-thread weights ----
    const int u2 = tid & 63;
    float wih0[DIN], wih1[DIN], whh0[HS], whh1[HS];
#pragma unroll
    for (int k = 0; k < DIN; k++) { wih0[k] = W_ih[k*G4 + u2]; wih1[k] = W_ih[k*G4 + u2 + 64]; }
#pragma unroll
    for (int k = 0; k < HS; k++)  { whh0[k] = W_hh[k*G4 + u2]; whh1[k] = W_hh[k*G4 + u2 + 64]; }
    const float bu0 = bias[u2], bu1 = bias[u2 + 64];

    const int hq = tid & 31;
    const int nq = tid >> 5;   // 0..7
    float wq[HS];
#pragma unroll
    for (int k = 0; k < HS; k++) wq[k] = W_q[k*HS + hq];
    const float bqv = b_q[hq];
    const float wdv = W_d[hq];
    const float bdv = b_d[0];

    // ---- stage adj rows to LDS once (row stride ADJW to kill bank conflicts) ----
    {
        const int n16_per_row = KPAD / 8;           // 316 uint4 per row
        for (int i = tid; i < ROWS * n16_per_row; i += 256) {
            int r = i / n16_per_row, o = i - r * n16_per_row;
            ((uint4*)(adj_lds + r * ADJW))[o] =
                ((const uint4*)(adj_bf + (size_t)(base + r) * KPAD))[o];
        }
    }
    for (int i = tid; i < ROWS * HPAD; i += 256) {
        (&h_lds[0][0])[i] = 0.0f;
        (&c_lds[0][0])[i] = 0.0f;
    }
    __syncthreads();

    for (int t = 0; t < TT; t++) {
        const unsigned phase = (unsigned)(t + 1);

        // ---- P1b: q = tanh(h @ W_q + b_q) ----
#pragma unroll
        for (int j = 0; j < 2; j++) {
            const int nn = nq + j*8;
            float a = bqv;
#pragma unroll
            for (int k4 = 0; k4 < HS/4; k4++) {
                float4 hv = *(const float4*)&h_lds[nn][k4*4];
                a = fmaf(hv.x, wq[k4*4+0], a);
                a = fmaf(hv.y, wq[k4*4+1], a);
                a = fmaf(hv.z, wq[k4*4+2], a);
                a = fmaf(hv.w, wq[k4*4+3], a);
            }
            q_lds[nn][hq] = tanh_fast(a);
        }
        __syncthreads();

        // ---- publish q: packed uint, agent-scope relaxed (write-through to LLC) ----
        {
            ushort_t* qbuf = qT + (size_t)(t & 1) * (HS * KPAD);
            const int h0 = tid >> 3;       // 0..31
            const int pr = tid & 7;        // node pair
            unsigned val = (unsigned)f2bf(q_lds[2*pr][h0])
                         | ((unsigned)f2bf(q_lds[2*pr + 1][h0]) << 16);
            unsigned* p = (unsigned*)(qbuf + (size_t)h0 * KPAD + base) + pr;
            __hip_atomic_store(p, val, __ATOMIC_RELAXED, __HIP_MEMORY_SCOPE_AGENT);
        }
        // drain own store to the LLC before this block's flag can be raised
        asm volatile("s_waitcnt vmcnt(0)" ::: "memory");
        __syncthreads();

        // ---- barrier ARRIVE: one relaxed flag store ----
        if (tid == 0) {
            __hip_atomic_store(flags + blk * FLAGSTRIDE, phase,
                               __ATOMIC_RELAXED, __HIP_MEMORY_SCOPE_AGENT);
        }

        // ==== overlap window: block-local work while other blocks arrive ====
        {
            const int node = tid >> 4, k = tid & 15;
            const int gn = base + node;
            x_lds[node][k] = (gn < BSN) ? x[(size_t)gn * (TT*DIN) + (size_t)t*DIN + k] : 0.0f;
        }
#pragma unroll
        for (int j = 0; j < 4; j++) {
            const int nn = wv*4 + j;
            float a0 = bu0, a1 = bu1;
#pragma unroll
            for (int k4 = 0; k4 < DIN/4; k4++) {
                float4 xv = *(const float4*)&x_lds[nn][k4*4];
                a0 = fmaf(xv.x, wih0[k4*4+0], a0); a1 = fmaf(xv.x, wih1[k4*4+0], a1);
                a0 = fmaf(xv.y, wih0[k4*4+1], a0); a1 = fmaf(xv.y, wih1[k4*4+1], a1);
                a0 = fmaf(xv.z, wih0[k4*4+2], a0); a1 = fmaf(xv.z, wih1[k4*4+2], a1);
                a0 = fmaf(xv.w, wih0[k4*4+3], a0); a1 = fmaf(xv.w, wih1[k4*4+3], a1);
            }
#pragma unroll
            for (int k4 = 0; k4 < HS/4; k4++) {
                float4 hv = *(const float4*)&h_lds[nn][k4*4];
                a0 = fmaf(hv.x, whh0[k4*4+0], a0); a1 = fmaf(hv.x, whh1[k4*4+0], a1);
                a0 = fmaf(hv.y, whh0[k4*4+1], a0); a1 = fmaf(hv.y, whh1[k4*4+1], a1);
                a0 = fmaf(hv.z, whh0[k4*4+2], a0); a1 = fmaf(hv.z, whh1[k4*4+2], a1);
                a0 = fmaf(hv.w, whh0[k4*4+3], a0); a1 = fmaf(hv.w, whh1[k4*4+3], a1);
            }
            gates_lds[nn][u2]      = sigmoid_fast(a0);
            gates_lds[nn][u2 + 64] = (u2 < HS) ? tanh_fast(a1) : sigmoid_fast(a1);
        }

        // ---- barrier WAIT: thread i polls block i's flag (L2-bypassing load) ----
        if (tid < NBLK) {
            const unsigned* f = flags + tid * FLAGSTRIDE;
            while (__hip_atomic_load(f, __ATOMIC_RELAXED, __HIP_MEMORY_SCOPE_AGENT) < phase)
                __builtin_amdgcn_s_sleep(1);
        }
        __syncthreads();

        // ---- P2: agg = adj(LDS) @ q(LLC) via mfma_f32_16x16x32_bf16 ----
        {
            const ushort_t* qbuf = qT + (size_t)(t & 1) * (HS * KPAD);
            floatx4 acc0 = {0.f,0.f,0.f,0.f}, acc1 = {0.f,0.f,0.f,0.f};
            const int mcol = lane & 15;
            const int kb   = lane >> 4;
            const ushort_t* arow = adj_lds + mcol * ADJW + kb*8;   // LDS
            const u64_t* q0 = (const u64_t*)(qbuf + (size_t)mcol        * KPAD) + kb*2;
            const u64_t* q1 = (const u64_t*)(qbuf + (size_t)(mcol + 16) * KPAD) + kb*2;
            const int cbeg = wv * 20;
            const int cend = (cbeg + 20 < NCHUNK) ? cbeg + 20 : NCHUNK;
#pragma unroll 4
            for (int c = cbeg; c < cend; c++) {
                bf16x8 av = *(const bf16x8*)(arow + c*32);
                union { bf16x8 v; u64_t u[2]; } b0, b1;
                b0.u[0] = __hip_atomic_load(q0 + c*8,     __ATOMIC_RELAXED, __HIP_MEMORY_SCOPE_AGENT);
                b0.u[1] = __hip_atomic_load(q0 + c*8 + 1, __ATOMIC_RELAXED, __HIP_MEMORY_SCOPE_AGENT);
                b1.u[0] = __hip_atomic_load(q1 + c*8,     __ATOMIC_RELAXED, __HIP_MEMORY_SCOPE_AGENT);
                b1.u[1] = __hip_atomic_load(q1 + c*8 + 1, __ATOMIC_RELAXED, __HIP_MEMORY_SCOPE_AGENT);
                acc0 = __builtin_amdgcn_mfma_f32_16x16x32_bf16(av, b0.v, acc0, 0, 0, 0);
                acc1 = __builtin_amdgcn_mfma_f32_16x16x32_bf16(av, b1.v, acc1, 0, 0, 0);
            }
            // D layout: col=lane&15, row=(lane>>4)*4+reg
#pragma unroll
            for (int r = 0; r < 4; r++) {
                part[wv][0][kb*4 + r][mcol] = acc0[r];
                part[wv][1][kb*4 + r][mcol] = acc1[r];
            }
        }
        __syncthreads();

        // ---- P3: cell/hidden update + fused output head ----
        {
            const int ntile = hq >> 4, col = hq & 15;
#pragma unroll
            for (int j = 0; j < 2; j++) {
                const int nn = nq + j*8;
                float agg = part[0][ntile][nn][col] + part[1][ntile][nn][col]
                          + part[2][ntile][nn][col] + part[3][ntile][nn][col];
                float iv = gates_lds[nn][hq];
                float fv = gates_lds[nn][HS + hq];
                float gv = gates_lds[nn][2*HS + hq];
                float ov = gates_lds[nn][3*HS + hq];
                float cv = fv * (c_lds[nn][hq] + agg) + iv * gv;
                float hv = ov * tanh_fast(cv);
                c_lds[nn][hq] = cv;
                h_lds[nn][hq] = hv;
                float p = hv * wdv;
                p += __shfl_xor(p, 16);
                p += __shfl_xor(p, 8);
                p += __shfl_xor(p, 4);
                p += __shfl_xor(p, 2);
                p += __shfl_xor(p, 1);
                if (hq == 0) {
                    int gn = base + nn;
                    if (gn < BSN) out[(size_t)gn * TT + t] = p + bdv;
                }
            }
        }
        __syncthreads();
    }
}

extern "C" void kernel_launch(void* const* d_in, const int* in_sizes, int n_in,
                              void* d_out, int out_size, void* d_ws, size_t ws_size,
                              hipStream_t stream) {
    const float* x    = (const float*)d_in[0];
    const float* adj  = (const float*)d_in[1];
    const float* W_ih = (const float*)d_in[2];
    const float* W_hh = (const float*)d_in[3];
    const float* bias = (const float*)d_in[4];
    const float* W_q  = (const float*)d_in[5];
    const float* b_q  = (const float*)d_in[6];
    const float* W_d  = (const float*)d_in[7];
    const float* b_d  = (const float*)d_in[8];
    float* out = (float*)d_out;

    // ws: adj_bf16 [2512][2528] (12.7 MB) | qT [2][32][2528] (316 KB) | flags (10 KB)
    ushort_t* adj_bf = (ushort_t*)d_ws;
    ushort_t* qT = adj_bf + (size_t)MPAD * KPAD;
    unsigned* flags = (unsigned*)(qT + (size_t)2 * HS * KPAD);

    hipLaunchKernelGGL(prep, dim3(2048), dim3(256), 0, stream, adj, adj_bf, qT, flags);

    const ushort_t* adj_bf_c = adj_bf;
    void* args[] = {
        (void*)&x, (void*)&W_ih, (void*)&W_hh, (void*)&bias, (void*)&W_q,
        (void*)&b_q, (void*)&W_d, (void*)&b_d, (void*)&adj_bf_c, (void*)&qT,
        (void*)&flags, (void*)&out
    };
    hipLaunchCooperativeKernel((void*)rgcn_main, dim3(NBLK), dim3(256), args, 0, stream);
}

// Round 7
// 3019.991 us; speedup vs baseline: 6.1408x; 1.5501x over previous
//
#include <hip/hip_runtime.h>
#include <hip/hip_bf16.h>

// Problem constants
#define BSN   2500   // nodes
#define TT    400    // time steps
#define DIN   16     // input dim
#define HS    32     // hidden dim
#define G4    128    // 4*HS
#define NBLK  157    // blocks (16 rows each)
#define ROWS  16     // nodes per block (MFMA M-tile)
#define MPAD  (NBLK * ROWS)   // 2512 padded rows
#define KPAD  2528            // 79*32 (R3-proven)
#define NCHUNK 79
#define ADJW  2536            // adj LDS row stride (ushorts)
#define HPAD  36              // fp32 LDS row pad
#define FLAGSTRIDE 16         // uints between flags (64 B)

// workspace layout (bytes)
#define WS_FLAGS_OFF  0
#define WS_ADJ_OFF    16384
#define WS_ADJ_BYTES  ((size_t)MPAD * KPAD * 2)            // 12,700,672
#define WS_QT_OFF     (WS_ADJ_OFF + WS_ADJ_BYTES)
#define QT_SLICE      ((size_t)HS * KPAD)                  // elements per step-slice
#define WS_NEED_RING  (WS_QT_OFF + (size_t)TT * QT_SLICE * 2)   // ~77.4 MB
#define WS_NEED_PAR   (WS_QT_OFF + 2 * QT_SLICE * 2)

typedef __attribute__((ext_vector_type(8))) __bf16 bf16x8;
typedef __attribute__((ext_vector_type(4))) float floatx4;
typedef unsigned short ushort_t;
typedef unsigned long long u64_t;

__device__ __forceinline__ float sigmoid_fast(float v) {
    return 1.0f / (1.0f + __expf(-v));
}
__device__ __forceinline__ float tanh_fast(float v) {
    float e = __expf(2.0f * v);
    return 1.0f - 2.0f / (e + 1.0f);
}
__device__ __forceinline__ ushort_t f2bf(float f) {
    union { float f; unsigned u; } x; x.f = f;
    unsigned r = x.u + 0x7fffu + ((x.u >> 16) & 1u);  // RNE
    return (ushort_t)(r >> 16);
}

// Sentinel: if the cooperative launch is rejected at submit time, out keeps
// 12345.0 -> absmax ~1.23e4 (vs 1.0156 "untouched", 3.9e-3 "correct").
__global__ void sentinel(float* __restrict__ out, int n) {
    int i = blockIdx.x * blockDim.x + threadIdx.x;
    if (i < n) out[i] = 12345.0f;
}

// Per-launch prep: zero flags; adj fp32 -> bf16 zero-padded; zero first 2 qT
// slices (parity-path safety; ring path needs no zeroing — pad cols multiply
// adj=0 and 0xAA-poison bf16 is finite).
__global__ void prep(const float* __restrict__ adj, ushort_t* __restrict__ adj_bf,
                     ushort_t* __restrict__ qT, unsigned* __restrict__ flags) {
    const size_t idx0 = (size_t)blockIdx.x * blockDim.x + threadIdx.x;
    const size_t stride = (size_t)gridDim.x * blockDim.x;
    const size_t total = (size_t)MPAD * KPAD;
    for (size_t idx = idx0; idx < total; idx += stride) {
        int r = (int)(idx / KPAD);
        int k = (int)(idx - (size_t)r * KPAD);
        float v = (r < BSN && k < BSN) ? adj[(size_t)r * BSN + k] : 0.0f;
        adj_bf[idx] = f2bf(v);
    }
    for (size_t idx = idx0; idx < 2 * QT_SLICE; idx += stride) qT[idx] = 0;
    if (idx0 < NBLK * FLAGSTRIDE) flags[idx0] = 0;
}

#define QLOAD(p) __hip_atomic_load((p), __ATOMIC_RELAXED, __HIP_MEMORY_SCOPE_AGENT)

// Ring-mode P2 inner: NC contiguous chunks from cbeg, PLAIN b128 loads
// (fresh addresses every step -> no stale-L2 hazard), depth-2 pipeline with
// 4-chunk groups. Buffer = 16 bf16x8 = 64 VGPRs; all indices compile-time.
template<int NC>
__device__ __forceinline__ void p2_ring(const ushort_t* __restrict__ arow,
                                        const ushort_t* __restrict__ q0r,
                                        const ushort_t* __restrict__ q1r,
                                        const int cbeg,
                                        floatx4& acc0, floatx4& acc1) {
    constexpr int NG = (NC + 3) / 4;
    bf16x8 c0[2][4], c1[2][4];
#pragma unroll
    for (int j = 0; j < 4; j++) {
        if (j < NC) {
            const int c = cbeg + j;
            c0[0][j] = *(const bf16x8*)(q0r + c*32);
            c1[0][j] = *(const bf16x8*)(q1r + c*32);
        }
    }
#pragma unroll
    for (int g = 0; g < NG; g++) {
        const int pb = g & 1, nb = (g + 1) & 1;
        if (g + 1 < NG) {
#pragma unroll
            for (int j = 0; j < 4; j++) {
                const int ci = 4*(g+1) + j;
                if (ci < NC) {
                    const int c = cbeg + ci;
                    c0[nb][j] = *(const bf16x8*)(q0r + c*32);
                    c1[nb][j] = *(const bf16x8*)(q1r + c*32);
                }
            }
        }
#pragma unroll
        for (int j = 0; j < 4; j++) {
            const int ci = 4*g + j;
            if (ci < NC) {
                const int c = cbeg + ci;
                bf16x8 av = *(const bf16x8*)(arow + c*32);
                acc0 = __builtin_amdgcn_mfma_f32_16x16x32_bf16(av, c0[pb][j], acc0, 0, 0, 0);
                acc1 = __builtin_amdgcn_mfma_f32_16x16x32_bf16(av, c1[pb][j], acc1, 0, 0, 0);
            }
        }
    }
}

// Persistent cooperative kernel — R3-proven skeleton.
// RING=true : qT is a per-step ring (plain pipelined loads in P2).
// RING=false: qT is the 2-slot parity buffer (R3's atomic loads, verbatim).
// __launch_bounds__(256,2): cap VGPR at 256 — hypothesis: coop launch is
// rejected when VGPR>256 (R4/R5/R6 sentinel evidence).
template<bool RING>
__global__ void __launch_bounds__(256, 2) rgcn_main(
    const float* __restrict__ x,      // [BSN][TT][DIN]
    const float* __restrict__ W_ih,   // [DIN][G4]
    const float* __restrict__ W_hh,   // [HS][G4]
    const float* __restrict__ bias,   // [G4]
    const float* __restrict__ W_q,    // [HS][HS]
    const float* __restrict__ b_q,    // [HS]
    const float* __restrict__ W_d,    // [HS]
    const float* __restrict__ b_d,    // [1]
    const ushort_t* __restrict__ adj_bf, // [MPAD][KPAD] bf16
    ushort_t* __restrict__ qT,        // ring: [TT][HS][KPAD]; parity: [2][HS][KPAD]
    unsigned* __restrict__ flags,     // [NBLK] generation flags, FLAGSTRIDE apart
    float* __restrict__ out)          // [BSN][TT]
{
    const int tid  = threadIdx.x;
    const int blk  = blockIdx.x;
    const int base = blk * ROWS;
    const int wv   = tid >> 6;
    const int lane = tid & 63;

    __shared__ __align__(16) ushort_t adj_lds[ROWS * ADJW];   // ~81 KB, staged once
    __shared__ __align__(16) float x_lds[ROWS][DIN];
    __shared__ __align__(16) float h_lds[ROWS][HPAD];
    __shared__ __align__(16) float c_lds[ROWS][HPAD];
    __shared__ __align__(16) float q_lds[ROWS][HPAD];
    __shared__ float gates_lds[ROWS][G4];
    __shared__ float part[4][2][16][16];

    // ---- persistent per-thread weights ----
    const int u2 = tid & 63;
    float wih0[DIN], wih1[DIN], whh0[HS], whh1[HS];
#pragma unroll
    for (int k = 0; k < DIN; k++) { wih0[k] = W_ih[k*G4 + u2]; wih1[k] = W_ih[k*G4 + u2 + 64]; }
#pragma unroll
    for (int k = 0; k < HS; k++)  { whh0[k] = W_hh[k*G4 + u2]; whh1[k] = W_hh[k*G4 + u2 + 64]; }
    const float bu0 = bias[u2], bu1 = bias[u2 + 64];

    const int hq = tid & 31;
    const int nq = tid >> 5;   // 0..7
    float wq[HS];
#pragma unroll
    for (int k = 0; k < HS; k++) wq[k] = W_q[k*HS + hq];
    const float bqv = b_q[hq];
    const float wdv = W_d[hq];
    const float bdv = b_d[0];

    // ---- stage adj rows to LDS once ----
    {
        const int n16_per_row = KPAD / 8;           // 316 uint4 per row
        for (int i = tid; i < ROWS * n16_per_row; i += 256) {
            int r = i / n16_per_row, o = i - r * n16_per_row;
            ((uint4*)(adj_lds + r * ADJW))[o] =
                ((const uint4*)(adj_bf + (size_t)(base + r) * KPAD))[o];
        }
    }
    for (int i = tid; i < ROWS * HPAD; i += 256) {
        (&h_lds[0][0])[i] = 0.0f;
        (&c_lds[0][0])[i] = 0.0f;
    }
    __syncthreads();

    for (int t = 0; t < TT; t++) {
        const unsigned phase = (unsigned)(t + 1);
        ushort_t* qbuf = qT + (size_t)(RING ? t : (t & 1)) * QT_SLICE;

        // ---- P1b: q = tanh(h @ W_q + b_q) ----
#pragma unroll
        for (int j = 0; j < 2; j++) {
            const int nn = nq + j*8;
            float a = bqv;
#pragma unroll
            for (int k4 = 0; k4 < HS/4; k4++) {
                float4 hv = *(const float4*)&h_lds[nn][k4*4];
                a = fmaf(hv.x, wq[k4*4+0], a);
                a = fmaf(hv.y, wq[k4*4+1], a);
                a = fmaf(hv.z, wq[k4*4+2], a);
                a = fmaf(hv.w, wq[k4*4+3], a);
            }
            q_lds[nn][hq] = tanh_fast(a);
        }
        __syncthreads();

        // ---- publish q: packed uint, agent-scope relaxed (write-through to LLC) ----
        {
            const int h0 = tid >> 3;       // 0..31
            const int pr = tid & 7;        // node pair
            unsigned val = (unsigned)f2bf(q_lds[2*pr][h0])
                         | ((unsigned)f2bf(q_lds[2*pr + 1][h0]) << 16);
            unsigned* p = (unsigned*)(qbuf + (size_t)h0 * KPAD + base) + pr;
            __hip_atomic_store(p, val, __ATOMIC_RELAXED, __HIP_MEMORY_SCOPE_AGENT);
        }
        // drain own store to the LLC before this block's flag can be raised
        asm volatile("s_waitcnt vmcnt(0)" ::: "memory");
        __syncthreads();

        // ---- barrier ARRIVE: one relaxed flag store ----
        if (tid == 0) {
            __hip_atomic_store(flags + blk * FLAGSTRIDE, phase,
                               __ATOMIC_RELAXED, __HIP_MEMORY_SCOPE_AGENT);
        }

        // ==== overlap window: block-local work while other blocks arrive ====
        {
            const int node = tid >> 4, k = tid & 15;
            const int gn = base + node;
            x_lds[node][k] = (gn < BSN) ? x[(size_t)gn * (TT*DIN) + (size_t)t*DIN + k] : 0.0f;
        }
#pragma unroll
        for (int j = 0; j < 4; j++) {
            const int nn = wv*4 + j;
            float a0 = bu0, a1 = bu1;
#pragma unroll
            for (int k4 = 0; k4 < DIN/4; k4++) {
                float4 xv = *(const float4*)&x_lds[nn][k4*4];
                a0 = fmaf(xv.x, wih0[k4*4+0], a0); a1 = fmaf(xv.x, wih1[k4*4+0], a1);
                a0 = fmaf(xv.y, wih0[k4*4+1], a0); a1 = fmaf(xv.y, wih1[k4*4+1], a1);
                a0 = fmaf(xv.z, wih0[k4*4+2], a0); a1 = fmaf(xv.z, wih1[k4*4+2], a1);
                a0 = fmaf(xv.w, wih0[k4*4+3], a0); a1 = fmaf(xv.w, wih1[k4*4+3], a1);
            }
#pragma unroll
            for (int k4 = 0; k4 < HS/4; k4++) {
                float4 hv = *(const float4*)&h_lds[nn][k4*4];
                a0 = fmaf(hv.x, whh0[k4*4+0], a0); a1 = fmaf(hv.x, whh1[k4*4+0], a1);
                a0 = fmaf(hv.y, whh0[k4*4+1], a0); a1 = fmaf(hv.y, whh1[k4*4+1], a1);
                a0 = fmaf(hv.z, whh0[k4*4+2], a0); a1 = fmaf(hv.z, whh1[k4*4+2], a1);
                a0 = fmaf(hv.w, whh0[k4*4+3], a0); a1 = fmaf(hv.w, whh1[k4*4+3], a1);
            }
            gates_lds[nn][u2]      = sigmoid_fast(a0);
            gates_lds[nn][u2 + 64] = (u2 < HS) ? tanh_fast(a1) : sigmoid_fast(a1);
        }

        // ---- barrier WAIT: thread i polls block i's flag ----
        if (tid < NBLK) {
            const unsigned* f = flags + tid * FLAGSTRIDE;
            while (__hip_atomic_load(f, __ATOMIC_RELAXED, __HIP_MEMORY_SCOPE_AGENT) < phase)
                __builtin_amdgcn_s_sleep(1);
        }
        __syncthreads();

        // ---- P2: agg = adj(LDS) @ q(LLC) ----
        {
            floatx4 acc0 = {0.f,0.f,0.f,0.f}, acc1 = {0.f,0.f,0.f,0.f};
            const int mcol = lane & 15;
            const int kb   = lane >> 4;
            const ushort_t* arow = adj_lds + mcol * ADJW + kb*8;   // LDS

            if constexpr (RING) {
                // fresh addresses -> plain pipelined b128 loads
                const ushort_t* q0r = qbuf + (size_t)mcol        * KPAD + kb*8;
                const ushort_t* q1r = qbuf + (size_t)(mcol + 16) * KPAD + kb*8;
                if (wv < 3) p2_ring<20>(arow, q0r, q1r, wv * 20, acc0, acc1);
                else        p2_ring<19>(arow, q0r, q1r, 60,      acc0, acc1);
            } else {
                // R3-verbatim: L2-bypassing atomic u64 loads
                const u64_t* q0 = (const u64_t*)(qbuf + (size_t)mcol        * KPAD) + kb*2;
                const u64_t* q1 = (const u64_t*)(qbuf + (size_t)(mcol + 16) * KPAD) + kb*2;
#pragma unroll 4
                for (int c = wv; c < NCHUNK; c += 4) {
                    bf16x8 av = *(const bf16x8*)(arow + c*32);
                    union { u64_t u[2]; bf16x8 v; } b0, b1;
                    b0.u[0] = QLOAD(q0 + c*8);
                    b0.u[1] = QLOAD(q0 + c*8 + 1);
                    b1.u[0] = QLOAD(q1 + c*8);
                    b1.u[1] = QLOAD(q1 + c*8 + 1);
                    acc0 = __builtin_amdgcn_mfma_f32_16x16x32_bf16(av, b0.v, acc0, 0, 0, 0);
                    acc1 = __builtin_amdgcn_mfma_f32_16x16x32_bf16(av, b1.v, acc1, 0, 0, 0);
                }
            }

            // D layout: col=lane&15, row=(lane>>4)*4+reg
#pragma unroll
            for (int r = 0; r < 4; r++) {
                part[wv][0][kb*4 + r][mcol] = acc0[r];
                part[wv][1][kb*4 + r][mcol] = acc1[r];
            }
        }
        __syncthreads();

        // ---- P3: cell/hidden update + fused output head ----
        {
            const int ntile = hq >> 4, col = hq & 15;
#pragma unroll
            for (int j = 0; j < 2; j++) {
                const int nn = nq + j*8;
                float agg = part[0][ntile][nn][col] + part[1][ntile][nn][col]
                          + part[2][ntile][nn][col] + part[3][ntile][nn][col];
                float iv = gates_lds[nn][hq];
                float fv = gates_lds[nn][HS + hq];
                float gv = gates_lds[nn][2*HS + hq];
                float ov = gates_lds[nn][3*HS + hq];
                float cv = fv * (c_lds[nn][hq] + agg) + iv * gv;
                float hv = ov * tanh_fast(cv);
                c_lds[nn][hq] = cv;
                h_lds[nn][hq] = hv;
                float p = hv * wdv;
                p += __shfl_xor(p, 16);
                p += __shfl_xor(p, 8);
                p += __shfl_xor(p, 4);
                p += __shfl_xor(p, 2);
                p += __shfl_xor(p, 1);
                if (hq == 0) {
                    int gn = base + nn;
                    if (gn < BSN) out[(size_t)gn * TT + t] = p + bdv;
                }
            }
        }
        __syncthreads();
    }
}

extern "C" void kernel_launch(void* const* d_in, const int* in_sizes, int n_in,
                              void* d_out, int out_size, void* d_ws, size_t ws_size,
                              hipStream_t stream) {
    const float* x    = (const float*)d_in[0];
    const float* adj  = (const float*)d_in[1];
    const float* W_ih = (const float*)d_in[2];
    const float* W_hh = (const float*)d_in[3];
    const float* bias = (const float*)d_in[4];
    const float* W_q  = (const float*)d_in[5];
    const float* b_q  = (const float*)d_in[6];
    const float* W_d  = (const float*)d_in[7];
    const float* b_d  = (const float*)d_in[8];
    float* out = (float*)d_out;

    unsigned* flags = (unsigned*)((char*)d_ws + WS_FLAGS_OFF);
    ushort_t* adj_bf = (ushort_t*)((char*)d_ws + WS_ADJ_OFF);
    ushort_t* qT = (ushort_t*)((char*)d_ws + WS_QT_OFF);

    const bool ring = (ws_size >= WS_NEED_RING);   // constant across calls -> graph-safe

    // sentinel first: if the cooperative launch below is rejected, out keeps 12345.0
    hipLaunchKernelGGL(sentinel, dim3((out_size + 255) / 256), dim3(256), 0, stream,
                       out, out_size);
    hipLaunchKernelGGL(prep, dim3(2048), dim3(256), 0, stream, adj, adj_bf, qT, flags);

    const ushort_t* adj_bf_c = adj_bf;
    void* args[] = {
        (void*)&x, (void*)&W_ih, (void*)&W_hh, (void*)&bias, (void*)&W_q,
        (void*)&b_q, (void*)&W_d, (void*)&b_d, (void*)&adj_bf_c, (void*)&qT,
        (void*)&flags, (void*)&out
    };
    if (ring) {
        hipLaunchCooperativeKernel((void*)&rgcn_main<true>, dim3(NBLK), dim3(256),
                                   args, 0, stream);
    } else {
        hipLaunchCooperativeKernel((void*)&rgcn_main<false>, dim3(NBLK), dim3(256),
                                   args, 0, stream);
    }
}

// Round 8
// 2908.900 us; speedup vs baseline: 6.3753x; 1.0382x over previous
//
#include <hip/hip_runtime.h>
#include <hip/hip_bf16.h>

// Problem constants
#define BSN   2500   // nodes
#define TT    400    // time steps
#define DIN   16     // input dim
#define HS    32     // hidden dim
#define G4    128    // 4*HS
#define NBLK  157    // blocks (16 rows each)
#define NTHR  512    // 8 waves: 2 waves/SIMD for latency overlap
#define ROWS  16     // nodes per block (MFMA M-tile)
#define MPAD  (NBLK * ROWS)   // 2512 padded rows
#define KPAD  2528            // 79*32 (R3/R7-proven layout)
#define NCHUNK 79
#define ADJW  2536            // adj LDS row stride (ushorts)
#define HPAD  36              // fp32 LDS row pad
#define FLAGSTRIDE 16         // uints between flags (64 B)

// workspace layout (bytes) — identical to R7 (ring path proven to fit)
#define WS_FLAGS_OFF  0
#define WS_ADJ_OFF    16384
#define WS_ADJ_BYTES  ((size_t)MPAD * KPAD * 2)
#define WS_QT_OFF     (WS_ADJ_OFF + WS_ADJ_BYTES)
#define QT_SLICE      ((size_t)HS * KPAD)
#define WS_NEED_RING  (WS_QT_OFF + (size_t)TT * QT_SLICE * 2)   // ~77.4 MB

typedef __attribute__((ext_vector_type(8))) __bf16 bf16x8;
typedef __attribute__((ext_vector_type(4))) float floatx4;
typedef unsigned short ushort_t;
typedef unsigned long long u64_t;

__device__ __forceinline__ float sigmoid_fast(float v) {
    return 1.0f / (1.0f + __expf(-v));
}
__device__ __forceinline__ float tanh_fast(float v) {
    float e = __expf(2.0f * v);
    return 1.0f - 2.0f / (e + 1.0f);
}
__device__ __forceinline__ ushort_t f2bf(float f) {
    union { float f; unsigned u; } x; x.f = f;
    unsigned r = x.u + 0x7fffu + ((x.u >> 16) & 1u);  // RNE
    return (ushort_t)(r >> 16);
}

// Sentinel: if the cooperative launch is rejected at submit time, out keeps
// 12345.0 -> absmax ~1.23e4 (vs 1.0156 "untouched", 3.9e-3 "correct").
__global__ void sentinel(float* __restrict__ out, int n) {
    int i = blockIdx.x * blockDim.x + threadIdx.x;
    if (i < n) out[i] = 12345.0f;
}

// Per-launch prep (d_ws re-poisoned 0xAA before every timed launch).
__global__ void prep(const float* __restrict__ adj, ushort_t* __restrict__ adj_bf,
                     ushort_t* __restrict__ qT, unsigned* __restrict__ flags) {
    const size_t idx0 = (size_t)blockIdx.x * blockDim.x + threadIdx.x;
    const size_t stride = (size_t)gridDim.x * blockDim.x;
    const size_t total = (size_t)MPAD * KPAD;
    for (size_t idx = idx0; idx < total; idx += stride) {
        int r = (int)(idx / KPAD);
        int k = (int)(idx - (size_t)r * KPAD);
        float v = (r < BSN && k < BSN) ? adj[(size_t)r * BSN + k] : 0.0f;
        adj_bf[idx] = f2bf(v);
    }
    for (size_t idx = idx0; idx < 2 * QT_SLICE; idx += stride) qT[idx] = 0;
    if (idx0 < NBLK * FLAGSTRIDE) flags[idx0] = 0;
}

#define QLOAD(p) __hip_atomic_load((p), __ATOMIC_RELAXED, __HIP_MEMORY_SCOPE_AGENT)

// Ring-mode P2: full prefetch — ALL NC chunks' q loads issued before any MFMA
// (NC=10 -> 20 b128 loads, 80 VGPRs; vmcnt max 63 so all stay in flight).
// Exposed latency ~1 LLC RTT per wave; 2 waves/SIMD overlap even that.
template<int NC>
__device__ __forceinline__ void p2_full(const ushort_t* __restrict__ arow,
                                        const ushort_t* __restrict__ q0r,
                                        const ushort_t* __restrict__ q1r,
                                        const int cbeg,
                                        floatx4& acc0, floatx4& acc1) {
    bf16x8 b0[NC], b1[NC];
#pragma unroll
    for (int i = 0; i < NC; i++) {
        b0[i] = *(const bf16x8*)(q0r + (cbeg + i) * 32);
        b1[i] = *(const bf16x8*)(q1r + (cbeg + i) * 32);
    }
#pragma unroll
    for (int i = 0; i < NC; i++) {
        bf16x8 av = *(const bf16x8*)(arow + (cbeg + i) * 32);
        acc0 = __builtin_amdgcn_mfma_f32_16x16x32_bf16(av, b0[i], acc0, 0, 0, 0);
        acc1 = __builtin_amdgcn_mfma_f32_16x16x32_bf16(av, b1[i], acc1, 0, 0, 0);
    }
}

// Persistent cooperative kernel, 512 threads (8 waves), block b owns nodes
// [16b,16b+16). All per-phase work mappings are wave-local (no intra-phase
// cross-wave LDS deps). RING=true: per-step qT ring, plain prefetched loads.
// RING=false: 2-slot parity buffer + atomic loads (fallback, R7-proven).
template<bool RING>
__global__ void __launch_bounds__(NTHR, 2) rgcn_main(
    const float* __restrict__ x,      // [BSN][TT][DIN]
    const float* __restrict__ W_ih,   // [DIN][G4]
    const float* __restrict__ W_hh,   // [HS][G4]
    const float* __restrict__ bias,   // [G4]
    const float* __restrict__ W_q,    // [HS][HS]
    const float* __restrict__ b_q,    // [HS]
    const float* __restrict__ W_d,    // [HS]
    const float* __restrict__ b_d,    // [1]
    const ushort_t* __restrict__ adj_bf, // [MPAD][KPAD] bf16
    ushort_t* __restrict__ qT,        // ring: [TT][HS][KPAD]; parity: [2][HS][KPAD]
    unsigned* __restrict__ flags,     // [NBLK] generation flags, FLAGSTRIDE apart
    float* __restrict__ out)          // [BSN][TT]
{
    const int tid  = threadIdx.x;
    const int blk  = blockIdx.x;
    const int base = blk * ROWS;
    const int wv   = tid >> 6;        // wave 0..7
    const int lane = tid & 63;

    __shared__ __align__(16) ushort_t adj_lds[ROWS * ADJW];   // ~81 KB, staged once
    __shared__ __align__(16) float x_lds[ROWS][DIN];
    __shared__ __align__(16) float h_lds[ROWS][HPAD];
    __shared__ __align__(16) float c_lds[ROWS][HPAD];
    __shared__ __align__(16) float q_lds[ROWS][HPAD];
    __shared__ float gates_lds[ROWS][G4];
    __shared__ float part[8][2][16][16];      // [wave][ntile][row][col], 16 KB

    // ---- per-thread weights (compiler re-loads per step from L2 — fine) ----
    const int u2 = tid & 63;
    float wih0[DIN], wih1[DIN], whh0[HS], whh1[HS];
#pragma unroll
    for (int k = 0; k < DIN; k++) { wih0[k] = W_ih[k*G4 + u2]; wih1[k] = W_ih[k*G4 + u2 + 64]; }
#pragma unroll
    for (int k = 0; k < HS; k++)  { whh0[k] = W_hh[k*G4 + u2]; whh1[k] = W_hh[k*G4 + u2 + 64]; }
    const float bu0 = bias[u2], bu1 = bias[u2 + 64];

    // P1b/P3 mapping: thread = (node nq = tid>>5 in 0..15, hidden hq = tid&31) — wave-local
    const int hq = tid & 31;
    const int nq = tid >> 5;
    float wq[HS];
#pragma unroll
    for (int k = 0; k < HS; k++) wq[k] = W_q[k*HS + hq];
    const float bqv = b_q[hq];
    const float wdv = W_d[hq];
    const float bdv = b_d[0];

    // ---- stage adj rows to LDS once ----
    {
        const int n16_per_row = KPAD / 8;           // 316 uint4 per row
        for (int i = tid; i < ROWS * n16_per_row; i += NTHR) {
            int r = i / n16_per_row, o = i - r * n16_per_row;
            ((uint4*)(adj_lds + r * ADJW))[o] =
                ((const uint4*)(adj_bf + (size_t)(base + r) * KPAD))[o];
        }
    }
    for (int i = tid; i < ROWS * HPAD; i += NTHR) {
        (&h_lds[0][0])[i] = 0.0f;
        (&c_lds[0][0])[i] = 0.0f;
    }
    __syncthreads();

    for (int t = 0; t < TT; t++) {
        const unsigned phase = (unsigned)(t + 1);
        ushort_t* qbuf = qT + (size_t)(RING ? t : (t & 1)) * QT_SLICE;

        // ---- P1b: q = tanh(h @ W_q + b_q); one q value per thread (wave-local h rows) ----
        {
            float a = bqv;
#pragma unroll
            for (int k4 = 0; k4 < HS/4; k4++) {
                float4 hv = *(const float4*)&h_lds[nq][k4*4];
                a = fmaf(hv.x, wq[k4*4+0], a);
                a = fmaf(hv.y, wq[k4*4+1], a);
                a = fmaf(hv.z, wq[k4*4+2], a);
                a = fmaf(hv.w, wq[k4*4+3], a);
            }
            q_lds[nq][hq] = tanh_fast(a);
        }
        __syncthreads();

        // ---- publish q: packed uint, agent-scope relaxed (write-through to LLC) ----
        if (tid < 256) {
            const int h0 = tid >> 3;       // 0..31
            const int pr = tid & 7;        // node pair
            unsigned val = (unsigned)f2bf(q_lds[2*pr][h0])
                         | ((unsigned)f2bf(q_lds[2*pr + 1][h0]) << 16);
            unsigned* p = (unsigned*)(qbuf + (size_t)h0 * KPAD + base) + pr;
            __hip_atomic_store(p, val, __ATOMIC_RELAXED, __HIP_MEMORY_SCOPE_AGENT);
        }

        // ==== drain shadow: local work overlaps the store->LLC round trip ====
        // x_t stage: wave w loads x for its own nodes 2w, 2w+1 (lanes<32)
        if (lane < 32) {
            const int node = 2*wv + (lane >> 4), k = lane & 15;
            const int gn = base + node;
            x_lds[node][k] = (gn < BSN) ? x[(size_t)gn * (TT*DIN) + (size_t)t*DIN + k] : 0.0f;
        }
        // gates: wave w computes nodes 2w, 2w+1 (reads x_lds/h_lds wave-locally)
#pragma unroll
        for (int j = 0; j < 2; j++) {
            const int nn = 2*wv + j;
            float a0 = bu0, a1 = bu1;
#pragma unroll
            for (int k4 = 0; k4 < DIN/4; k4++) {
                float4 xv = *(const float4*)&x_lds[nn][k4*4];
                a0 = fmaf(xv.x, wih0[k4*4+0], a0); a1 = fmaf(xv.x, wih1[k4*4+0], a1);
                a0 = fmaf(xv.y, wih0[k4*4+1], a0); a1 = fmaf(xv.y, wih1[k4*4+1], a1);
                a0 = fmaf(xv.z, wih0[k4*4+2], a0); a1 = fmaf(xv.z, wih1[k4*4+2], a1);
                a0 = fmaf(xv.w, wih0[k4*4+3], a0); a1 = fmaf(xv.w, wih1[k4*4+3], a1);
            }
#pragma unroll
            for (int k4 = 0; k4 < HS/4; k4++) {
                float4 hv = *(const float4*)&h_lds[nn][k4*4];
                a0 = fmaf(hv.x, whh0[k4*4+0], a0); a1 = fmaf(hv.x, whh1[k4*4+0], a1);
                a0 = fmaf(hv.y, whh0[k4*4+1], a0); a1 = fmaf(hv.y, whh1[k4*4+1], a1);
                a0 = fmaf(hv.z, whh0[k4*4+2], a0); a1 = fmaf(hv.z, whh1[k4*4+2], a1);
                a0 = fmaf(hv.w, whh0[k4*4+3], a0); a1 = fmaf(hv.w, whh1[k4*4+3], a1);
            }
            gates_lds[nn][u2]      = sigmoid_fast(a0);
            gates_lds[nn][u2 + 64] = (u2 < HS) ? tanh_fast(a1) : sigmoid_fast(a1);
        }

        // ---- drain q stores, then arrive ----
        asm volatile("s_waitcnt vmcnt(0)" ::: "memory");
        __syncthreads();
        if (tid == 0) {
            __hip_atomic_store(flags + blk * FLAGSTRIDE, phase,
                               __ATOMIC_RELAXED, __HIP_MEMORY_SCOPE_AGENT);
        }

        // ---- wait: thread i polls block i's flag (pure spin) ----
        if (tid < NBLK) {
            const unsigned* f = flags + tid * FLAGSTRIDE;
            while (__hip_atomic_load(f, __ATOMIC_RELAXED, __HIP_MEMORY_SCOPE_AGENT) < phase) {}
        }
        __syncthreads();

        // ---- P2: agg = adj(LDS) @ q(LLC); wave w: contiguous chunks [10w, 10w+10) ----
        {
            floatx4 acc0 = {0.f,0.f,0.f,0.f}, acc1 = {0.f,0.f,0.f,0.f};
            const int mcol = lane & 15;
            const int kb   = lane >> 4;
            const ushort_t* arow = adj_lds + mcol * ADJW + kb*8;   // LDS

            if constexpr (RING) {
                const ushort_t* q0r = qbuf + (size_t)mcol        * KPAD + kb*8;
                const ushort_t* q1r = qbuf + (size_t)(mcol + 16) * KPAD + kb*8;
                if (wv < 7) p2_full<10>(arow, q0r, q1r, wv * 10, acc0, acc1);
                else        p2_full<9>(arow, q0r, q1r, 70,       acc0, acc1);
            } else {
                const u64_t* q0 = (const u64_t*)(qbuf + (size_t)mcol        * KPAD) + kb*2;
                const u64_t* q1 = (const u64_t*)(qbuf + (size_t)(mcol + 16) * KPAD) + kb*2;
                const int cbeg = wv * 10;
                const int cend = (cbeg + 10 < NCHUNK) ? cbeg + 10 : NCHUNK;
                for (int c = cbeg; c < cend; c++) {
                    bf16x8 av = *(const bf16x8*)(arow + c*32);
                    union { u64_t u[2]; bf16x8 v; } b0, b1;
                    b0.u[0] = QLOAD(q0 + c*8);
                    b0.u[1] = QLOAD(q0 + c*8 + 1);
                    b1.u[0] = QLOAD(q1 + c*8);
                    b1.u[1] = QLOAD(q1 + c*8 + 1);
                    acc0 = __builtin_amdgcn_mfma_f32_16x16x32_bf16(av, b0.v, acc0, 0, 0, 0);
                    acc1 = __builtin_amdgcn_mfma_f32_16x16x32_bf16(av, b1.v, acc1, 0, 0, 0);
                }
            }

            // D layout: col=lane&15, row=(lane>>4)*4+reg
#pragma unroll
            for (int r = 0; r < 4; r++) {
                part[wv][0][kb*4 + r][mcol] = acc0[r];
                part[wv][1][kb*4 + r][mcol] = acc1[r];
            }
        }
        __syncthreads();

        // ---- P3: cell/hidden update + fused output head (one (node,hidden)/thread) ----
        {
            const int ntile = hq >> 4, col = hq & 15;
            float agg = 0.0f;
#pragma unroll
            for (int w = 0; w < 8; w++) agg += part[w][ntile][nq][col];
            float iv = gates_lds[nq][hq];
            float fv = gates_lds[nq][HS + hq];
            float gv = gates_lds[nq][2*HS + hq];
            float ov = gates_lds[nq][3*HS + hq];
            float cv = fv * (c_lds[nq][hq] + agg) + iv * gv;
            float hv = ov * tanh_fast(cv);
            c_lds[nq][hq] = cv;
            h_lds[nq][hq] = hv;
            float p = hv * wdv;
            p += __shfl_xor(p, 16);
            p += __shfl_xor(p, 8);
            p += __shfl_xor(p, 4);
            p += __shfl_xor(p, 2);
            p += __shfl_xor(p, 1);
            if (hq == 0) {
                int gn = base + nq;
                if (gn < BSN) out[(size_t)gn * TT + t] = p + bdv;
            }
        }
        __syncthreads();
    }
}

extern "C" void kernel_launch(void* const* d_in, const int* in_sizes, int n_in,
                              void* d_out, int out_size, void* d_ws, size_t ws_size,
                              hipStream_t stream) {
    const float* x    = (const float*)d_in[0];
    const float* adj  = (const float*)d_in[1];
    const float* W_ih = (const float*)d_in[2];
    const float* W_hh = (const float*)d_in[3];
    const float* bias = (const float*)d_in[4];
    const float* W_q  = (const float*)d_in[5];
    const float* b_q  = (const float*)d_in[6];
    const float* W_d  = (const float*)d_in[7];
    const float* b_d  = (const float*)d_in[8];
    float* out = (float*)d_out;

    unsigned* flags = (unsigned*)((char*)d_ws + WS_FLAGS_OFF);
    ushort_t* adj_bf = (ushort_t*)((char*)d_ws + WS_ADJ_OFF);
    ushort_t* qT = (ushort_t*)((char*)d_ws + WS_QT_OFF);

    const bool ring = (ws_size >= WS_NEED_RING);   // constant across calls -> graph-safe

    // sentinel first: if the cooperative launch below is rejected, out keeps 12345.0
    hipLaunchKernelGGL(sentinel, dim3((out_size + 255) / 256), dim3(256), 0, stream,
                       out, out_size);
    hipLaunchKernelGGL(prep, dim3(2048), dim3(256), 0, stream, adj, adj_bf, qT, flags);

    const ushort_t* adj_bf_c = adj_bf;
    void* args[] = {
        (void*)&x, (void*)&W_ih, (void*)&W_hh, (void*)&bias, (void*)&W_q,
        (void*)&b_q, (void*)&W_d, (void*)&b_d, (void*)&adj_bf_c, (void*)&qT,
        (void*)&flags, (void*)&out
    };
    if (ring) {
        hipLaunchCooperativeKernel((void*)&rgcn_main<true>, dim3(NBLK), dim3(NTHR),
                                   args, 0, stream);
    } else {
        hipLaunchCooperativeKernel((void*)&rgcn_main<false>, dim3(NBLK), dim3(NTHR),
                                   args, 0, stream);
    }
}